// Round 7
// baseline (760.790 us; speedup 1.0000x reference)
//
#include <hip/hip_runtime.h>
#include <hip/hip_bf16.h>
#include <math.h>

typedef __bf16  bf16x8 __attribute__((ext_vector_type(8)));
typedef float   f32x4  __attribute__((ext_vector_type(4)));

#define MFMA16(a,b,c) __builtin_amdgcn_mfma_f32_16x16x32_bf16((a),(b),(c),0,0,0)

#define NBUCK 256
#define CAPG  8192      // max entries per bucket segment (mean ~6250, +24 sigma)
#define P1_ED 4096      // edges per p1 block
#define SPLIT 4         // emit-quarters per bucket (SPLIT=8 regressed: L3 misses on dup key reads)

__device__ __forceinline__ bf16x8 cvt8(const float* p) {
  const f32x4* q = (const f32x4*)p;
  f32x4 u = q[0], v = q[1];
  bf16x8 r;
  r[0]=(__bf16)u[0]; r[1]=(__bf16)u[1]; r[2]=(__bf16)u[2]; r[3]=(__bf16)u[3];
  r[4]=(__bf16)v[0]; r[5]=(__bf16)v[1]; r[6]=(__bf16)v[2]; r[7]=(__bf16)v[3];
  return r;
}

__device__ __forceinline__ float sigf(float x){ return 1.0f/(1.0f + __expf(-x)); }
__device__ __forceinline__ float tanhf_fast(float x){
  float ax = fabsf(x);
  float t = __expf(-2.f*ax);
  float r = (1.f - t)/(1.f + t);
  return copysignf(r, x);
}

// ---------------- pass 1 + fused weight prep (independent tail blocks) -------
// Blocks [0,nMain): block-aggregated bucket scatter of edges.
// Blocks [nMain,..): k_prep_all work (weights only; p1 is LDS-sort-heavy /
// DRAM-light, so this streaming tail rides in its DRAM slack).
__global__ __launch_bounds__(256) void k_p1_bucket(const int* __restrict__ ei,
                                                   unsigned int* __restrict__ entryBuf,
                                                   int* __restrict__ bCnt,
                                                   int E, int NW, int nMain,
                                                   const float* __restrict__ whh,
                                                   const float* __restrict__ w2,
                                                   const float* __restrict__ b2,
                                                   const float* __restrict__ fe_w1,
                                                   const float* __restrict__ lstm_wih,
                                                   const float* __restrict__ gm_w,
                                                   const float* __restrict__ fm_w,
                                                   __bf16* __restrict__ Mout,
                                                   float* __restrict__ wb,
                                                   __bf16* __restrict__ Wuv,
                                                   __bf16* __restrict__ Wc,
                                                   __bf16* __restrict__ Wih,
                                                   __bf16* __restrict__ R,
                                                   int P_, int G) {
  __shared__ unsigned int hin[NBUCK], hof[NBUCK], hcur[NBUCK], gbase[NBUCK];
  __shared__ unsigned int vals[P1_ED];
  __shared__ unsigned int gpos[P1_ED];
  __shared__ unsigned int totS;
  int tid = threadIdx.x;

  if ((int)blockIdx.x >= nMain) {
    // ---- prep_all tail ----
    int idx = ((int)blockIdx.x - nMain)*256 + tid;
    int n0 = P_*256*64;
    if (idx < n0) {
      int c = idx & 63; int r = (idx >> 6) & 255; int i = idx >> 14;
      const float* wh  = whh + ((size_t)i*256 + r)*64;
      const float* w2i = w2  + (size_t)i*64*64;
      float acc = 0.f;
      #pragma unroll 8
      for (int j=0;j<64;j++) acc += wh[j] * w2i[j*64 + c];
      Mout[idx] = (__bf16)acc;
      if (c == 0) {
        const float* b2i = b2 + i*64;
        float a2 = 0.f;
        for (int j=0;j<64;j++) a2 += wh[j]*b2i[j];
        wb[i*256 + r] = a2;
      }
      return;
    }
    idx -= n0;
    int nA = P_*128*64, nB = P_*64*32, nC = P_*256*64, nD = 128*64;
    if (idx < nA) {
      int k = idx & 63, j = (idx >> 6) & 127, i = idx >> 13;
      Wuv[idx] = (__bf16)fe_w1[(size_t)i*10240 + (j&63)*160 + (j>>6)*64 + k];
      return;
    }
    idx -= nA;
    if (idx < nB) {
      int k = idx & 31, j = (idx >> 5) & 63, i = idx >> 11;
      Wc[idx] = (__bf16)fe_w1[(size_t)i*10240 + j*160 + 128 + k];
      return;
    }
    idx -= nB;
    if (idx < nC) { Wih[idx] = (__bf16)lstm_wih[idx]; return; }
    idx -= nC;
    if (idx < nD) {
      int k = idx & 63, j = idx >> 6;
      float v = 0.f;
      if (j < G) v = gm_w[j*64 + k];
      else if (j >= 64 && j < 64 + G) v = fm_w[(j-64)*64 + k];
      R[idx] = (__bf16)v;
    }
    return;
  }

  // ---- p1 main ----
  hin[tid] = 0;
  __syncthreads();

  int e0 = blockIdx.x * P1_ED;
  unsigned int myb[16], myv[16];
  #pragma unroll
  for (int k=0;k<16;k++) {
    int e = e0 + k*256 + tid;
    if (e < E) {
      int d = ei[E + e];
      int b = d / NW;
      int dl = d - b*NW;
      myb[k] = (unsigned int)b;
      myv[k] = ((unsigned int)dl << 21) | (unsigned int)e;
      atomicAdd(&hin[b], 1u);
    } else myb[k] = 0xFFFFFFFFu;
  }
  __syncthreads();

  unsigned int cntb = hin[tid];
  hof[tid] = cntb;
  __syncthreads();
  #pragma unroll
  for (int off=1; off<NBUCK; off<<=1) {
    unsigned int a = (tid >= off) ? hof[tid-off] : 0u;
    __syncthreads();
    hof[tid] += a;
    __syncthreads();
  }
  unsigned int excl = hof[tid] - cntb;
  if (cntb > 0) gbase[tid] = (unsigned int)atomicAdd(&bCnt[tid], (int)cntb);
  if (tid == NBUCK-1) totS = excl + cntb;
  __syncthreads();
  hof[tid] = excl;
  hcur[tid] = excl;
  __syncthreads();

  #pragma unroll
  for (int k=0;k<16;k++) {
    if (myb[k] != 0xFFFFFFFFu) {
      unsigned int b = myb[k];
      unsigned int pos = atomicAdd(&hcur[b], 1u);
      vals[pos] = myv[k];
      unsigned int go = gbase[b] + (pos - hof[b]);
      gpos[pos] = (go < CAPG) ? (b*CAPG + go) : 0xFFFFFFFFu;
    }
  }
  __syncthreads();
  unsigned int tot = totS;
  for (unsigned int i = tid; i < tot; i += 256) {
    unsigned int g = gpos[i];
    if (g != 0xFFFFFFFFu) entryBuf[g] = vals[i];
  }
}

// -------- gscan + streaming tails (runs between p1 and p2) -------------------
// Block 0: exclusive scan of clamped bucket counts -> gstart.
// Blocks [1, 1+zB): zero sacc0 (full-BW streaming, NOT stealing p2's DRAM).
// Blocks [1+zB,..): step-0 prep_uv (U,V from x) -- Wuv ready since p1 is done.
__global__ __launch_bounds__(512) void k_gscan_fused(const int* __restrict__ bCnt,
                                                     int* __restrict__ gstart,
                                                     const float* __restrict__ x,
                                                     const __bf16* __restrict__ Wuv0,
                                                     __bf16* __restrict__ U,
                                                     __bf16* __restrict__ V,
                                                     float* __restrict__ sacc0,
                                                     int N, int nGroups, int zB) {
  int tid = threadIdx.x;
  if (blockIdx.x == 0) {
    __shared__ int s[512];
    int v = (tid < NBUCK) ? min(bCnt[tid], CAPG) : 0;
    s[tid] = v;
    __syncthreads();
    #pragma unroll
    for (int off=1; off<512; off<<=1) {
      int a = (tid >= off) ? s[tid-off] : 0;
      __syncthreads();
      s[tid] += a;
      __syncthreads();
    }
    if (tid < NBUCK) gstart[tid] = s[tid] - v;
    return;
  }
  int tb = (int)blockIdx.x - 1;
  if (tb < zB) {
    f32x4 z4 = {0.f,0.f,0.f,0.f};
    f32x4* p = (f32x4*)sacc0;
    size_t tot4 = (size_t)N*16;
    size_t nt = (size_t)zB*512;
    for (size_t i = (size_t)tb*512 + tid; i < tot4; i += nt) p[i] = z4;
    return;
  }
  int wave = (tb - zB)*8 + (tid >> 6);
  if (wave >= nGroups) return;
  int lane = tid & 63, row = lane & 15, quad = lane >> 4;
  int m0 = wave * 16;
  const float* arow = x + (size_t)(m0 + row)*64 + quad*8;
  bf16x8 a0 = cvt8(arow);
  bf16x8 a1 = cvt8(arow + 32);
  f32x4 z = {0.f,0.f,0.f,0.f};
  f32x4 acc[8];
  #pragma unroll
  for (int t=0;t<8;t++) acc[t] = z;
  #pragma unroll
  for (int t=0;t<8;t++) {
    const __bf16* b = Wuv0 + (t*16 + row)*64 + quad*8;
    acc[t] = MFMA16(a0, *(const bf16x8*)b,        acc[t]);
    acc[t] = MFMA16(a1, *(const bf16x8*)(b + 32), acc[t]);
  }
  #pragma unroll
  for (int t=0;t<8;t++) {
    __bf16* dst = (t < 4) ? U : V;
    int fcol = (t & 3)*16 + row;
    #pragma unroll
    for (int r=0;r<4;r++)
      dst[(size_t)(m0 + quad*4 + r)*64 + fcol] = (__bf16)acc[t][r];
  }
}

// ---------------- pass 2: per-bucket counting sort + streaming emit ----------
// Pure sort+emit again (tails moved out: p2 is DRAM-saturated on the random
// edge_attr row gather; extra streaming here costs ~60% of its serial time).
__global__ __launch_bounds__(512) void k_p2_sort(const unsigned int* __restrict__ entryBuf,
                                                 const int* __restrict__ bCnt,
                                                 const int* __restrict__ gstart,
                                                 const int* __restrict__ ei,
                                                 const float* __restrict__ ea,
                                                 int2* __restrict__ DS,
                                                 __bf16* __restrict__ EA,
                                                 int* __restrict__ degi,
                                                 int E, int N, int NW) {
  __shared__ unsigned int hist[512], hof[512], hcur[512];
  __shared__ unsigned int evals[CAPG];
  int b = blockIdx.x >> 2;         // SPLIT == 4
  int q = blockIdx.x & 3;
  int tid = threadIdx.x;
  unsigned int cnt = (unsigned int)min(bCnt[b], CAPG);
  const unsigned int* seg = entryBuf + (size_t)b*CAPG;

  hist[tid] = 0;
  __syncthreads();
  for (unsigned int i = tid; i < cnt; i += 512) atomicAdd(&hist[seg[i] >> 21], 1u);
  __syncthreads();

  unsigned int h = hist[tid];
  hof[tid] = h;
  __syncthreads();
  #pragma unroll
  for (int off=1; off<512; off<<=1) {
    unsigned int a = (tid >= off) ? hof[tid-off] : 0u;
    __syncthreads();
    hof[tid] += a;
    __syncthreads();
  }
  unsigned int excl = hof[tid] - h;
  int d0 = b*NW + tid;
  if (tid < NW && d0 < N) degi[d0] = (int)h;
  hcur[tid] = excl;
  __syncthreads();

  for (unsigned int i = tid; i < cnt; i += 512) {
    unsigned int v = seg[i];
    unsigned int pos = atomicAdd(&hcur[v >> 21], 1u);
    evals[pos] = v;
  }
  __syncthreads();

  unsigned int gp0 = (unsigned int)gstart[b];
  unsigned int lo = (cnt * (unsigned int)q) >> 2;
  unsigned int hi = (cnt * (unsigned int)(q+1)) >> 2;
  for (unsigned int i = lo + tid; i < hi; i += 512) {
    unsigned int v = evals[i];
    unsigned int e = v & 0x1FFFFFu;
    int dl = (int)(v >> 21);
    int d  = b*NW + dl;
    int s  = ei[e];
    size_t p = (size_t)gp0 + i;
    int2 ds; ds.x = d; ds.y = s;
    DS[p] = ds;
    const float* row = ea + (size_t)e*32;
    bf16x8 r0 = cvt8(row);
    bf16x8 r1 = cvt8(row + 8);
    bf16x8 r2 = cvt8(row + 16);
    bf16x8 r3 = cvt8(row + 24);
    __bf16* o = EA + p*32;
    *(bf16x8*)(o)      = r0;
    *(bf16x8*)(o + 8)  = r1;
    *(bf16x8*)(o + 16) = r2;
    *(bf16x8*)(o + 24) = r3;
  }
}

// ---------------- edge-centric aggregation + zero tail -----------------------
// Blocks [0,nMain): 64 sorted edges/wave, ballot runs, atomic run flushes.
// Blocks [nMain,..): zero next step's sacc buffer (aggr is L2-gather/latency-
// bound -> real DRAM slack for this tail).
__global__ __launch_bounds__(256) void k_aggr_e(const int2* __restrict__ DS,
                                                const __bf16* __restrict__ EA,
                                                const __bf16* __restrict__ Wc,
                                                const float* __restrict__ b1,
                                                const __bf16* __restrict__ U,
                                                const __bf16* __restrict__ V,
                                                float* __restrict__ sacc, int E,
                                                float* __restrict__ sZero, int Nn,
                                                int nMain) {
  __shared__ float ldsb[4][16*68];   // stride 68: conflict-free (2 lanes/bank)
  int tid = threadIdx.x;

  if ((int)blockIdx.x >= nMain) {
    if (sZero) {
      f32x4 z4 = {0.f,0.f,0.f,0.f};
      f32x4* p = (f32x4*)sZero;
      size_t tot4 = (size_t)Nn*16;
      size_t nt = (size_t)(gridDim.x - nMain)*256;
      for (size_t i = ((size_t)blockIdx.x - nMain)*256 + tid; i < tot4; i += nt) p[i] = z4;
    }
    return;
  }

  int wib = tid >> 6;
  int lane = tid & 63, row = lane & 15, quad = lane >> 4;

  int e0 = ((int)blockIdx.x*4 + wib) * 64;
  if (e0 >= E) return;

  int eidx = min(e0 + lane, E - 1);
  int2 dsv = DS[eidx];
  int dv = dsv.x;
  int sv = dsv.y;

  int prevd = __shfl_up(dv, 1);
  unsigned long long bmask = __ballot((lane == 0) || (dv != prevd));

  bf16x8 a[4];
  #pragma unroll
  for (int st=0;st<4;st++)
    a[st] = *(const bf16x8*)(EA + (size_t)(e0 + st*16 + row)*32 + quad*8);

  bf16x8 bfr[4]; float bias[4];
  #pragma unroll
  for (int t=0;t<4;t++) {
    bfr[t] = *(const bf16x8*)(Wc + (t*16 + row)*32 + quad*8);
    bias[t] = b1[t*16 + row];
  }

  __bf16 uu[2][16], vv[2][16];
  #pragma unroll
  for (int r=0;r<16;r++) {
    int s = __builtin_amdgcn_readlane(sv, r);
    int d = __builtin_amdgcn_readlane(dv, r);
    vv[0][r] = V[(size_t)s*64 + lane];
    uu[0][r] = U[(size_t)d*64 + lane];
  }

  float acc = 0.f;
  int dcur = __builtin_amdgcn_readlane(dv, 0);
  float* L = &ldsb[wib][0];
  f32x4 z = {0.f,0.f,0.f,0.f};

  #pragma unroll
  for (int st=0; st<4; st++) {
    const int cur = st & 1, nxt = cur ^ 1;
    #pragma unroll
    for (int t=0;t<4;t++) {
      f32x4 c4 = MFMA16(a[st], bfr[t], z);
      #pragma unroll
      for (int r=0;r<4;r++)
        L[(quad*4 + r)*68 + t*16 + row] = c4[r] + bias[t];
    }
    if (st < 3) {
      #pragma unroll
      for (int r=0;r<16;r++) {
        int s = __builtin_amdgcn_readlane(sv, (st+1)*16 + r);
        int d = __builtin_amdgcn_readlane(dv, (st+1)*16 + r);
        vv[nxt][r] = V[(size_t)s*64 + lane];
        uu[nxt][r] = U[(size_t)d*64 + lane];
      }
    }
    #pragma unroll
    for (int r=0;r<16;r++) {
      const int idx = st*16 + r;
      if (idx > 0 && (bmask & (1ull << idx))) {
        unsafeAtomicAdd(&sacc[(size_t)dcur*64 + lane], acc);
        acc = 0.f;
        dcur = __builtin_amdgcn_readlane(dv, idx);
      }
      if (e0 + idx < E) {
        float t2 = (float)uu[cur][r] + (float)vv[cur][r] + L[r*68 + lane];
        acc += t2 > 0.f ? t2 : 0.f;
      }
    }
  }
  unsafeAtomicAdd(&sacc[(size_t)dcur*64 + lane], acc);
}

// ---------------- K4: gates + LSTM update, with fused epilogues ----------------
__global__ __launch_bounds__(256) void k_lstm(const float* __restrict__ h_in,
                                              const float* __restrict__ sacc,
                                              const int* __restrict__ degi,
                                              const __bf16* __restrict__ Wih,
                                              const __bf16* __restrict__ Mw,
                                              const float* __restrict__ wb,
                                              const float* __restrict__ bih,
                                              const float* __restrict__ bhh,
                                              float* __restrict__ h_out,
                                              float* __restrict__ c,
                                              const __bf16* __restrict__ Wuvn,
                                              __bf16* __restrict__ U,
                                              __bf16* __restrict__ V,
                                              const __bf16* __restrict__ R,
                                              const float* __restrict__ gm_b,
                                              const float* __restrict__ fm_b,
                                              float* __restrict__ out,
                                              int nGroups, int G,
                                              int has_c, int write_c,
                                              int fuse_uv, int terminal) {
  __shared__ float hlds[4][16*68];
  __shared__ float red[4][4][16];
  int tid = threadIdx.x;
  int wave = (blockIdx.x*blockDim.x + tid) >> 6;
  int wib  = tid >> 6;
  int lane = tid & 63, row = lane & 15, quad = lane >> 4;
  bool active = (wave < nGroups);
  int m0 = wave * 16;

  float hn_[4][4];
  if (active) {
    float wbv[4][4], bsv[4][4];
    #pragma unroll
    for (int g=0; g<4; g++)
      #pragma unroll
      for (int t=0; t<4; t++) {
        int dcol = g*64 + t*16 + row;
        wbv[g][t] = wb[dcol];
        bsv[g][t] = bih[dcol] + bhh[dcol];
      }
    float dgv[4];
    #pragma unroll
    for (int r=0;r<4;r++) {
      int node = m0 + quad*4 + r;
      dgv[r] = (float)degi[node];
    }
    float cold[4][4];
    if (has_c) {
      #pragma unroll
      for (int t=0;t<4;t++)
        #pragma unroll
        for (int r=0;r<4;r++)
          cold[t][r] = c[(size_t)(m0 + quad*4 + r)*64 + t*16 + row];
    } else {
      #pragma unroll
      for (int t=0;t<4;t++)
        #pragma unroll
        for (int r=0;r<4;r++) cold[t][r] = 0.f;
    }

    const float* hrow = h_in + (size_t)(m0 + row)*64 + quad*8;
    const float* srow = sacc + (size_t)(m0 + row)*64 + quad*8;
    bf16x8 ah0 = cvt8(hrow), ah1 = cvt8(hrow + 32);
    bf16x8 as0 = cvt8(srow), as1 = cvt8(srow + 32);
    f32x4 z = {0.f,0.f,0.f,0.f};
    f32x4 acc[16];
    #pragma unroll
    for (int t=0;t<16;t++) acc[t] = z;
    #pragma unroll
    for (int t=0;t<16;t++) {
      const __bf16* bw = Wih + (t*16 + row)*64 + quad*8;
      const __bf16* bm = Mw  + (t*16 + row)*64 + quad*8;
      acc[t] = MFMA16(ah0, *(const bf16x8*)bw,        acc[t]);
      acc[t] = MFMA16(ah1, *(const bf16x8*)(bw + 32), acc[t]);
      acc[t] = MFMA16(as0, *(const bf16x8*)bm,        acc[t]);
      acc[t] = MFMA16(as1, *(const bf16x8*)(bm + 32), acc[t]);
    }
    #pragma unroll
    for (int r=0;r<4;r++) {
      int node = m0 + quad*4 + r;
      float dg = dgv[r];
      #pragma unroll
      for (int t=0;t<4;t++) {
        float gi = acc[t][r]     + dg*wbv[0][t] + bsv[0][t];
        float gf = acc[4+t][r]   + dg*wbv[1][t] + bsv[1][t];
        float gg = acc[8+t][r]   + dg*wbv[2][t] + bsv[2][t];
        float go = acc[12+t][r]  + dg*wbv[3][t] + bsv[3][t];
        size_t ci = (size_t)node*64 + t*16 + row;
        float cn = sigf(gf)*cold[t][r] + sigf(gi)*tanhf_fast(gg);
        float hn = sigf(go)*tanhf_fast(cn);
        if (write_c) c[ci] = cn;
        if (!terminal) h_out[ci] = hn;
        hn_[t][r] = hn;
      }
    }
  }

  if (!(fuse_uv | terminal)) return;

  if (active) {
    #pragma unroll
    for (int t=0;t<4;t++)
      #pragma unroll
      for (int r=0;r<4;r++)
        hlds[wib][(quad*4 + r)*68 + t*16 + row] = hn_[t][r];
  }
  __syncthreads();

  if (fuse_uv && active) {
    const float* hr = &hlds[wib][row*68 + quad*8];
    bf16x8 a0 = cvt8(hr);
    bf16x8 a1 = cvt8(hr + 32);
    f32x4 z = {0.f,0.f,0.f,0.f};
    f32x4 au[8];
    #pragma unroll
    for (int t=0;t<8;t++) au[t] = z;
    #pragma unroll
    for (int t=0;t<8;t++) {
      const __bf16* b = Wuvn + (t*16 + row)*64 + quad*8;
      au[t] = MFMA16(a0, *(const bf16x8*)b,        au[t]);
      au[t] = MFMA16(a1, *(const bf16x8*)(b + 32), au[t]);
    }
    #pragma unroll
    for (int t=0;t<8;t++) {
      __bf16* dst = (t < 4) ? U : V;
      int fcol = (t & 3)*16 + row;
      #pragma unroll
      for (int r=0;r<4;r++)
        dst[(size_t)(m0 + quad*4 + r)*64 + fcol] = (__bf16)au[t][r];
    }
  }

  if (terminal) {
    float local[4] = {0.f,0.f,0.f,0.f};
    if (active) {
      const float* hr = &hlds[wib][row*68 + quad*8];
      bf16x8 a0 = cvt8(hr);
      bf16x8 a1 = cvt8(hr + 32);
      f32x4 z = {0.f,0.f,0.f,0.f};
      f32x4 ar[8];
      #pragma unroll
      for (int t=0;t<8;t++) {
        const __bf16* b = R + (t*16 + row)*64 + quad*8;
        ar[t] = MFMA16(a0, *(const bf16x8*)b, z);
        ar[t] = MFMA16(a1, *(const bf16x8*)(b + 32), ar[t]);
      }
      #pragma unroll
      for (int t=0;t<4;t++) {
        int d = t*16 + row;
        if (d < G) {
          float gb = gm_b[d], fb = fm_b[d];
          #pragma unroll
          for (int r=0;r<4;r++) {
            float gv = ar[t][r]   + gb;
            float hv = ar[4+t][r] + fb;
            local[t] += sigf(gv) * hv;
          }
        }
      }
    }
    #pragma unroll
    for (int t=0;t<4;t++) {
      float v = local[t];
      v += __shfl_xor(v, 16);
      v += __shfl_xor(v, 32);
      local[t] = v;
    }
    if (quad == 0)
      #pragma unroll
      for (int t=0;t<4;t++) red[wib][t][row] = local[t];
    __syncthreads();
    if (tid < 64) {
      int d = tid;
      if (d < G) {
        float v = red[0][d>>4][d&15] + red[1][d>>4][d&15] + red[2][d>>4][d&15] + red[3][d>>4][d&15];
        unsafeAtomicAdd(out + d, v);
      }
    }
  }
}

extern "C" void kernel_launch(void* const* d_in, const int* in_sizes, int n_in,
                              void* d_out, int out_size, void* d_ws, size_t ws_size,
                              hipStream_t stream) {
  const float* x         = (const float*)d_in[0];
  const float* edge_attr = (const float*)d_in[1];
  const int*   edge_index= (const int*)  d_in[2];
  const float* fe_w1     = (const float*)d_in[3];
  const float* fe_b1     = (const float*)d_in[4];
  const float* fe_w2     = (const float*)d_in[5];
  const float* fe_b2     = (const float*)d_in[6];
  const float* lstm_wih  = (const float*)d_in[7];
  const float* lstm_whh  = (const float*)d_in[8];
  const float* lstm_bih  = (const float*)d_in[9];
  const float* lstm_bhh  = (const float*)d_in[10];
  const float* gm_w      = (const float*)d_in[11];
  const float* gm_b      = (const float*)d_in[12];
  const float* fm_w      = (const float*)d_in[13];
  const float* fm_b      = (const float*)d_in[14];
  float* out = (float*)d_out;

  const int N  = in_sizes[0] / 64;
  const int E  = in_sizes[1] / 32;
  const int P_ = in_sizes[3] / (64*160);
  const int G  = in_sizes[11] / 64;
  const int nGroups = N / 16;
  const int NW = (N + NBUCK - 1) / NBUCK;   // nodes per bucket (<=512 required)

  // ---- workspace layout (float units) ----
  float* f = (float*)d_ws;
  size_t o = 0;
  float* hA  = f + o;  o += (size_t)N*64;
  float* hB  = f + o;  o += (size_t)N*64;   // for P_==2: dead as h-buffer -> reused as sacc1
  float* cB  = f + o;  o += (size_t)N*64;
  float* sB  = f + o;  o += (size_t)N*64;
  float* wb  = f + o;  o += (size_t)P_*256;
  __bf16* U  = (__bf16*)(f + o);  o += (size_t)N*32;
  __bf16* V  = (__bf16*)(f + o);  o += (size_t)N*32;
  int* degi   = (int*)(f + o);    o += (size_t)N;
  int* bCnt   = (int*)(f + o);    o += NBUCK;
  int* gstart = (int*)(f + o);    o += NBUCK;
  o = (o + 15) & ~(size_t)15;                        // 64B align
  int2* DS    = (int2*)(f + o);   o += (size_t)E*2;  // packed (dst,src), sorted
  o = (o + 15) & ~(size_t)15;                        // 64B align: EA row == 1 line
  __bf16* EA  = (__bf16*)(f + o); o += ((size_t)E + 64)*16;  // sorted edge_attr, bf16, padded
  unsigned int* entryBuf = (unsigned int*)(f + o); o += (size_t)NBUCK*CAPG;
  __bf16* Wuv = (__bf16*)(f + o);
  __bf16* Wc  = Wuv + (size_t)P_*128*64;
  __bf16* Wih = Wc  + (size_t)P_*64*32;
  __bf16* Mw  = Wih + (size_t)P_*256*64;
  __bf16* Rw  = Mw  + (size_t)P_*256*64;

  // sacc ping-pong: hB is provably unused as an h-buffer when P_==2
  // (terminal step never writes h_out), so reuse it -> zero extra footprint.
  const int pingpong = (P_ == 2);

  hipMemsetAsync(out, 0, (size_t)out_size*sizeof(float), stream);
  hipMemsetAsync(bCnt, 0, NBUCK*sizeof(int), stream);

  // p1 (+ prep_all tail blocks)
  int nb1 = (E + P1_ED - 1) / P1_ED;
  {
    int tot = P_*256*64 + P_*128*64 + P_*64*32 + P_*256*64 + 128*64;
    int prepBlocks = (tot + 255)/256;
    k_p1_bucket<<<nb1 + prepBlocks, 256, 0, stream>>>(edge_index, entryBuf, bCnt, E, NW, nb1,
                                                      lstm_whh, fe_w2, fe_b2, fe_w1, lstm_wih,
                                                      gm_w, fm_w, Mw, wb, Wuv, Wc, Wih, Rw,
                                                      P_, G);
  }

  // gscan (+ zero sacc0 + step-0 prep_uv tails, at full BW between p1 and p2)
  {
    int zB = 256;
    int uvB = (nGroups + 7) / 8;
    k_gscan_fused<<<1 + zB + uvB, 512, 0, stream>>>(bCnt, gstart, x, Wuv, U, V, sB,
                                                    N, nGroups, zB);
  }

  // p2: pure sort + emit
  k_p2_sort<<<NBUCK*SPLIT, 512, 0, stream>>>(entryBuf, bCnt, gstart, edge_index,
                                             edge_attr, DS, EA, degi, E, N, NW);

  int nodeBlocks = (nGroups + 3) / 4;
  int chunkBlocks = ((E + 63)/64 + 3) / 4;

  for (int i = 0; i < P_; i++) {
    const float* h_in = (i == 0) ? x : ((i & 1) ? hA : hB);
    float*       h_out = (i & 1) ? hB : hA;
    int terminal = (i == P_ - 1);
    int fuse_uv  = !terminal;

    float* sacc_i = (pingpong && (i & 1)) ? hB : sB;
    float* sZero  = (pingpong && !terminal) ? (((i+1) & 1) ? hB : sB) : (float*)nullptr;

    if (!pingpong && i > 0)
      hipMemsetAsync(sB, 0, (size_t)N*64*sizeof(float), stream);

    int zB2 = sZero ? 320 : 0;
    k_aggr_e<<<chunkBlocks + zB2, 256, 0, stream>>>(DS, EA, Wc + (size_t)i*64*32,
                                                    fe_b1 + i*64, U, V, sacc_i, E,
                                                    sZero, N, chunkBlocks);
    k_lstm<<<nodeBlocks, 256, 0, stream>>>(h_in, sacc_i, degi,
                                           Wih + (size_t)i*256*64, Mw + (size_t)i*256*64,
                                           wb + i*256, lstm_bih + i*256, lstm_bhh + i*256,
                                           h_out, cB,
                                           Wuv + (size_t)(i+1 < P_ ? i+1 : 0)*128*64, U, V,
                                           Rw, gm_b, fm_b, out,
                                           nGroups, G,
                                           /*has_c=*/(i > 0), /*write_c=*/(i < P_-1),
                                           fuse_uv, terminal);
  }
}

// Round 8
// 756.514 us; speedup vs baseline: 1.0057x; 1.0057x over previous
//
#include <hip/hip_runtime.h>
#include <hip/hip_bf16.h>
#include <math.h>

typedef __bf16  bf16x8 __attribute__((ext_vector_type(8)));
typedef float   f32x4  __attribute__((ext_vector_type(4)));

#define MFMA16(a,b,c) __builtin_amdgcn_mfma_f32_16x16x32_bf16((a),(b),(c),0,0,0)

#define NBUCK 256
#define CAPG  8192      // max entries per bucket segment (mean ~6250, +24 sigma)
#define P1_ED 4096      // edges per p1 block
#define SPLIT 4         // emit-quarters per bucket (SPLIT=8 regressed: L3 misses on dup key reads)

__device__ __forceinline__ bf16x8 cvt8(const float* p) {
  const f32x4* q = (const f32x4*)p;
  f32x4 u = q[0], v = q[1];
  bf16x8 r;
  r[0]=(__bf16)u[0]; r[1]=(__bf16)u[1]; r[2]=(__bf16)u[2]; r[3]=(__bf16)u[3];
  r[4]=(__bf16)v[0]; r[5]=(__bf16)v[1]; r[6]=(__bf16)v[2]; r[7]=(__bf16)v[3];
  return r;
}

__device__ __forceinline__ float sigf(float x){ return 1.0f/(1.0f + __expf(-x)); }
__device__ __forceinline__ float tanhf_fast(float x){
  float ax = fabsf(x);
  float t = __expf(-2.f*ax);
  float r = (1.f - t)/(1.f + t);
  return copysignf(r, x);
}

// ---------------- pass 1 + ALL independent streaming tails -------------------
// Blocks [0,nMain):                 block-aggregated bucket scatter of edges.
// Blocks [nMain, +prepB):           weight prep (prep_all).
// Blocks [nMain+prepB, +zB):        zero sacc0.
// Blocks [nMain+prepB+zB, ..):      step-0 prep_uv from x, reading fe_w1
//                                   DIRECTLY (fp32, inline cvt) -> no intra-
//                                   kernel dependency on Wuv.
// p1 main is LDS-sort-heavy / DRAM-light: proven slack for these tails.
__global__ __launch_bounds__(256) void k_p1_bucket(const int* __restrict__ ei,
                                                   unsigned int* __restrict__ entryBuf,
                                                   int* __restrict__ bCnt,
                                                   int E, int NW, int nMain,
                                                   int prepB, int zB,
                                                   const float* __restrict__ whh,
                                                   const float* __restrict__ w2,
                                                   const float* __restrict__ b2,
                                                   const float* __restrict__ fe_w1,
                                                   const float* __restrict__ lstm_wih,
                                                   const float* __restrict__ gm_w,
                                                   const float* __restrict__ fm_w,
                                                   __bf16* __restrict__ Mout,
                                                   float* __restrict__ wb,
                                                   __bf16* __restrict__ Wuv,
                                                   __bf16* __restrict__ Wc,
                                                   __bf16* __restrict__ Wih,
                                                   __bf16* __restrict__ R,
                                                   int P_, int G,
                                                   const float* __restrict__ x,
                                                   __bf16* __restrict__ U,
                                                   __bf16* __restrict__ V,
                                                   float* __restrict__ sacc0,
                                                   int N, int nGroups) {
  __shared__ unsigned int hin[NBUCK], hof[NBUCK], hcur[NBUCK], gbase[NBUCK];
  __shared__ unsigned int vals[P1_ED];
  __shared__ unsigned int gpos[P1_ED];
  __shared__ unsigned int totS;
  int tid = threadIdx.x;

  if ((int)blockIdx.x >= nMain) {
    int tb = (int)blockIdx.x - nMain;
    if (tb < prepB) {
      // ---- prep_all tail ----
      int idx = tb*256 + tid;
      int n0 = P_*256*64;
      if (idx < n0) {
        int c = idx & 63; int r = (idx >> 6) & 255; int i = idx >> 14;
        const float* wh  = whh + ((size_t)i*256 + r)*64;
        const float* w2i = w2  + (size_t)i*64*64;
        float acc = 0.f;
        #pragma unroll 8
        for (int j=0;j<64;j++) acc += wh[j] * w2i[j*64 + c];
        Mout[idx] = (__bf16)acc;
        if (c == 0) {
          const float* b2i = b2 + i*64;
          float a2 = 0.f;
          for (int j=0;j<64;j++) a2 += wh[j]*b2i[j];
          wb[i*256 + r] = a2;
        }
        return;
      }
      idx -= n0;
      int nA = P_*128*64, nB = P_*64*32, nC = P_*256*64, nD = 128*64;
      if (idx < nA) {
        int k = idx & 63, j = (idx >> 6) & 127, i = idx >> 13;
        Wuv[idx] = (__bf16)fe_w1[(size_t)i*10240 + (j&63)*160 + (j>>6)*64 + k];
        return;
      }
      idx -= nA;
      if (idx < nB) {
        int k = idx & 31, j = (idx >> 5) & 63, i = idx >> 11;
        Wc[idx] = (__bf16)fe_w1[(size_t)i*10240 + j*160 + 128 + k];
        return;
      }
      idx -= nB;
      if (idx < nC) { Wih[idx] = (__bf16)lstm_wih[idx]; return; }
      idx -= nC;
      if (idx < nD) {
        int k = idx & 63, j = idx >> 6;
        float v = 0.f;
        if (j < G) v = gm_w[j*64 + k];
        else if (j >= 64 && j < 64 + G) v = fm_w[(j-64)*64 + k];
        R[idx] = (__bf16)v;
      }
      return;
    }
    tb -= prepB;
    if (tb < zB) {
      // ---- zero sacc0 ----
      f32x4 z4 = {0.f,0.f,0.f,0.f};
      f32x4* p = (f32x4*)sacc0;
      size_t tot4 = (size_t)N*16;
      size_t nt = (size_t)zB*256;
      for (size_t i = (size_t)tb*256 + tid; i < tot4; i += nt) p[i] = z4;
      return;
    }
    tb -= zB;
    // ---- step-0 prep_uv: U,V from x, weights straight from fe_w1 (fp32) ----
    int wave = tb*4 + (tid >> 6);
    if (wave >= nGroups) return;
    int lane = tid & 63, row = lane & 15, quad = lane >> 4;
    int m0 = wave * 16;
    const float* arow = x + (size_t)(m0 + row)*64 + quad*8;
    bf16x8 a0 = cvt8(arow);
    bf16x8 a1 = cvt8(arow + 32);
    f32x4 z = {0.f,0.f,0.f,0.f};
    f32x4 acc[8];
    #pragma unroll
    for (int t=0;t<8;t++) acc[t] = z;
    #pragma unroll
    for (int t=0;t<8;t++) {
      int j = t*16 + row;
      const float* wrow = fe_w1 + (size_t)(j & 63)*160 + (j >> 6)*64 + quad*8;
      bf16x8 b0 = cvt8(wrow);
      bf16x8 b1 = cvt8(wrow + 32);
      acc[t] = MFMA16(a0, b0, acc[t]);
      acc[t] = MFMA16(a1, b1, acc[t]);
    }
    #pragma unroll
    for (int t=0;t<8;t++) {
      __bf16* dst = (t < 4) ? U : V;
      int fcol = (t & 3)*16 + row;
      #pragma unroll
      for (int r=0;r<4;r++)
        dst[(size_t)(m0 + quad*4 + r)*64 + fcol] = (__bf16)acc[t][r];
    }
    return;
  }

  // ---- p1 main ----
  hin[tid] = 0;
  __syncthreads();

  int e0 = blockIdx.x * P1_ED;
  unsigned int myb[16], myv[16];
  #pragma unroll
  for (int k=0;k<16;k++) {
    int e = e0 + k*256 + tid;
    if (e < E) {
      int d = ei[E + e];
      int b = d / NW;
      int dl = d - b*NW;
      myb[k] = (unsigned int)b;
      myv[k] = ((unsigned int)dl << 21) | (unsigned int)e;
      atomicAdd(&hin[b], 1u);
    } else myb[k] = 0xFFFFFFFFu;
  }
  __syncthreads();

  unsigned int cntb = hin[tid];
  hof[tid] = cntb;
  __syncthreads();
  #pragma unroll
  for (int off=1; off<NBUCK; off<<=1) {
    unsigned int a = (tid >= off) ? hof[tid-off] : 0u;
    __syncthreads();
    hof[tid] += a;
    __syncthreads();
  }
  unsigned int excl = hof[tid] - cntb;
  if (cntb > 0) gbase[tid] = (unsigned int)atomicAdd(&bCnt[tid], (int)cntb);
  if (tid == NBUCK-1) totS = excl + cntb;
  __syncthreads();
  hof[tid] = excl;
  hcur[tid] = excl;
  __syncthreads();

  #pragma unroll
  for (int k=0;k<16;k++) {
    if (myb[k] != 0xFFFFFFFFu) {
      unsigned int b = myb[k];
      unsigned int pos = atomicAdd(&hcur[b], 1u);
      vals[pos] = myv[k];
      unsigned int go = gbase[b] + (pos - hof[b]);
      gpos[pos] = (go < CAPG) ? (b*CAPG + go) : 0xFFFFFFFFu;
    }
  }
  __syncthreads();
  unsigned int tot = totS;
  for (unsigned int i = tid; i < tot; i += 256) {
    unsigned int g = gpos[i];
    if (g != 0xFFFFFFFFu) entryBuf[g] = vals[i];
  }
}

// ---------------- pass 2: counting sort + streaming emit ---------------------
// gstart computed INLINE per block (256-wide scan of bCnt, ~1us, parallel) --
// removes the separate gscan dispatch from the serial chain.
__global__ __launch_bounds__(512) void k_p2_sort(const unsigned int* __restrict__ entryBuf,
                                                 const int* __restrict__ bCnt,
                                                 const int* __restrict__ ei,
                                                 const float* __restrict__ ea,
                                                 int2* __restrict__ DS,
                                                 __bf16* __restrict__ EA,
                                                 int* __restrict__ degi,
                                                 int E, int N, int NW) {
  __shared__ unsigned int hist[512], hof[512], hcur[512];
  __shared__ unsigned int evals[CAPG];
  __shared__ unsigned int gp0S;
  int b = blockIdx.x >> 2;         // SPLIT == 4
  int q = blockIdx.x & 3;
  int tid = threadIdx.x;
  unsigned int cnt = (unsigned int)min(bCnt[b], CAPG);
  const unsigned int* seg = entryBuf + (size_t)b*CAPG;

  // inline gstart[b]: exclusive prefix over clamped bucket counts
  {
    unsigned int v = (tid < NBUCK) ? (unsigned int)min(bCnt[tid], CAPG) : 0u;
    hof[tid] = v;
    __syncthreads();
    #pragma unroll
    for (int off=1; off<512; off<<=1) {
      unsigned int a = (tid >= off) ? hof[tid-off] : 0u;
      __syncthreads();
      hof[tid] += a;
      __syncthreads();
    }
    if (tid == 0) gp0S = (b > 0) ? hof[b-1] : 0u;
    __syncthreads();
  }

  hist[tid] = 0;
  __syncthreads();
  for (unsigned int i = tid; i < cnt; i += 512) atomicAdd(&hist[seg[i] >> 21], 1u);
  __syncthreads();

  unsigned int h = hist[tid];
  hof[tid] = h;
  __syncthreads();
  #pragma unroll
  for (int off=1; off<512; off<<=1) {
    unsigned int a = (tid >= off) ? hof[tid-off] : 0u;
    __syncthreads();
    hof[tid] += a;
    __syncthreads();
  }
  unsigned int excl = hof[tid] - h;
  int d0 = b*NW + tid;
  if (tid < NW && d0 < N) degi[d0] = (int)h;
  hcur[tid] = excl;
  __syncthreads();

  for (unsigned int i = tid; i < cnt; i += 512) {
    unsigned int v = seg[i];
    unsigned int pos = atomicAdd(&hcur[v >> 21], 1u);
    evals[pos] = v;
  }
  __syncthreads();

  unsigned int gp0 = gp0S;
  unsigned int lo = (cnt * (unsigned int)q) >> 2;
  unsigned int hi = (cnt * (unsigned int)(q+1)) >> 2;
  for (unsigned int i = lo + tid; i < hi; i += 512) {
    unsigned int v = evals[i];
    unsigned int e = v & 0x1FFFFFu;
    int dl = (int)(v >> 21);
    int d  = b*NW + dl;
    int s  = ei[e];
    size_t p = (size_t)gp0 + i;
    int2 ds; ds.x = d; ds.y = s;
    DS[p] = ds;
    const float* row = ea + (size_t)e*32;
    bf16x8 r0 = cvt8(row);
    bf16x8 r1 = cvt8(row + 8);
    bf16x8 r2 = cvt8(row + 16);
    bf16x8 r3 = cvt8(row + 24);
    __bf16* o = EA + p*32;
    *(bf16x8*)(o)      = r0;
    *(bf16x8*)(o + 8)  = r1;
    *(bf16x8*)(o + 16) = r2;
    *(bf16x8*)(o + 24) = r3;
  }
}

// ---------------- edge-centric aggregation + zero tail -----------------------
__global__ __launch_bounds__(256) void k_aggr_e(const int2* __restrict__ DS,
                                                const __bf16* __restrict__ EA,
                                                const __bf16* __restrict__ Wc,
                                                const float* __restrict__ b1,
                                                const __bf16* __restrict__ U,
                                                const __bf16* __restrict__ V,
                                                float* __restrict__ sacc, int E,
                                                float* __restrict__ sZero, int Nn,
                                                int nMain) {
  __shared__ float ldsb[4][16*68];   // stride 68: conflict-free (2 lanes/bank)
  int tid = threadIdx.x;

  if ((int)blockIdx.x >= nMain) {
    if (sZero) {
      f32x4 z4 = {0.f,0.f,0.f,0.f};
      f32x4* p = (f32x4*)sZero;
      size_t tot4 = (size_t)Nn*16;
      size_t nt = (size_t)(gridDim.x - nMain)*256;
      for (size_t i = ((size_t)blockIdx.x - nMain)*256 + tid; i < tot4; i += nt) p[i] = z4;
    }
    return;
  }

  int wib = tid >> 6;
  int lane = tid & 63, row = lane & 15, quad = lane >> 4;

  int e0 = ((int)blockIdx.x*4 + wib) * 64;
  if (e0 >= E) return;

  int eidx = min(e0 + lane, E - 1);
  int2 dsv = DS[eidx];
  int dv = dsv.x;
  int sv = dsv.y;

  int prevd = __shfl_up(dv, 1);
  unsigned long long bmask = __ballot((lane == 0) || (dv != prevd));

  bf16x8 a[4];
  #pragma unroll
  for (int st=0;st<4;st++)
    a[st] = *(const bf16x8*)(EA + (size_t)(e0 + st*16 + row)*32 + quad*8);

  bf16x8 bfr[4]; float bias[4];
  #pragma unroll
  for (int t=0;t<4;t++) {
    bfr[t] = *(const bf16x8*)(Wc + (t*16 + row)*32 + quad*8);
    bias[t] = b1[t*16 + row];
  }

  __bf16 uu[2][16], vv[2][16];
  #pragma unroll
  for (int r=0;r<16;r++) {
    int s = __builtin_amdgcn_readlane(sv, r);
    int d = __builtin_amdgcn_readlane(dv, r);
    vv[0][r] = V[(size_t)s*64 + lane];
    uu[0][r] = U[(size_t)d*64 + lane];
  }

  float acc = 0.f;
  int dcur = __builtin_amdgcn_readlane(dv, 0);
  float* L = &ldsb[wib][0];
  f32x4 z = {0.f,0.f,0.f,0.f};

  #pragma unroll
  for (int st=0; st<4; st++) {
    const int cur = st & 1, nxt = cur ^ 1;
    #pragma unroll
    for (int t=0;t<4;t++) {
      f32x4 c4 = MFMA16(a[st], bfr[t], z);
      #pragma unroll
      for (int r=0;r<4;r++)
        L[(quad*4 + r)*68 + t*16 + row] = c4[r] + bias[t];
    }
    if (st < 3) {
      #pragma unroll
      for (int r=0;r<16;r++) {
        int s = __builtin_amdgcn_readlane(sv, (st+1)*16 + r);
        int d = __builtin_amdgcn_readlane(dv, (st+1)*16 + r);
        vv[nxt][r] = V[(size_t)s*64 + lane];
        uu[nxt][r] = U[(size_t)d*64 + lane];
      }
    }
    #pragma unroll
    for (int r=0;r<16;r++) {
      const int idx = st*16 + r;
      if (idx > 0 && (bmask & (1ull << idx))) {
        unsafeAtomicAdd(&sacc[(size_t)dcur*64 + lane], acc);
        acc = 0.f;
        dcur = __builtin_amdgcn_readlane(dv, idx);
      }
      if (e0 + idx < E) {
        float t2 = (float)uu[cur][r] + (float)vv[cur][r] + L[r*68 + lane];
        acc += t2 > 0.f ? t2 : 0.f;
      }
    }
  }
  unsafeAtomicAdd(&sacc[(size_t)dcur*64 + lane], acc);
}

// ---------------- K4: gates + LSTM update, with fused epilogues ----------------
__global__ __launch_bounds__(256) void k_lstm(const float* __restrict__ h_in,
                                              const float* __restrict__ sacc,
                                              const int* __restrict__ degi,
                                              const __bf16* __restrict__ Wih,
                                              const __bf16* __restrict__ Mw,
                                              const float* __restrict__ wb,
                                              const float* __restrict__ bih,
                                              const float* __restrict__ bhh,
                                              float* __restrict__ h_out,
                                              float* __restrict__ c,
                                              const __bf16* __restrict__ Wuvn,
                                              __bf16* __restrict__ U,
                                              __bf16* __restrict__ V,
                                              const __bf16* __restrict__ R,
                                              const float* __restrict__ gm_b,
                                              const float* __restrict__ fm_b,
                                              float* __restrict__ out,
                                              int nGroups, int G,
                                              int has_c, int write_c,
                                              int fuse_uv, int terminal) {
  __shared__ float hlds[4][16*68];
  __shared__ float red[4][4][16];
  int tid = threadIdx.x;
  int wave = (blockIdx.x*blockDim.x + tid) >> 6;
  int wib  = tid >> 6;
  int lane = tid & 63, row = lane & 15, quad = lane >> 4;
  bool active = (wave < nGroups);
  int m0 = wave * 16;

  float hn_[4][4];
  if (active) {
    float wbv[4][4], bsv[4][4];
    #pragma unroll
    for (int g=0; g<4; g++)
      #pragma unroll
      for (int t=0; t<4; t++) {
        int dcol = g*64 + t*16 + row;
        wbv[g][t] = wb[dcol];
        bsv[g][t] = bih[dcol] + bhh[dcol];
      }
    float dgv[4];
    #pragma unroll
    for (int r=0;r<4;r++) {
      int node = m0 + quad*4 + r;
      dgv[r] = (float)degi[node];
    }
    float cold[4][4];
    if (has_c) {
      #pragma unroll
      for (int t=0;t<4;t++)
        #pragma unroll
        for (int r=0;r<4;r++)
          cold[t][r] = c[(size_t)(m0 + quad*4 + r)*64 + t*16 + row];
    } else {
      #pragma unroll
      for (int t=0;t<4;t++)
        #pragma unroll
        for (int r=0;r<4;r++) cold[t][r] = 0.f;
    }

    const float* hrow = h_in + (size_t)(m0 + row)*64 + quad*8;
    const float* srow = sacc + (size_t)(m0 + row)*64 + quad*8;
    bf16x8 ah0 = cvt8(hrow), ah1 = cvt8(hrow + 32);
    bf16x8 as0 = cvt8(srow), as1 = cvt8(srow + 32);
    f32x4 z = {0.f,0.f,0.f,0.f};
    f32x4 acc[16];
    #pragma unroll
    for (int t=0;t<16;t++) acc[t] = z;
    #pragma unroll
    for (int t=0;t<16;t++) {
      const __bf16* bw = Wih + (t*16 + row)*64 + quad*8;
      const __bf16* bm = Mw  + (t*16 + row)*64 + quad*8;
      acc[t] = MFMA16(ah0, *(const bf16x8*)bw,        acc[t]);
      acc[t] = MFMA16(ah1, *(const bf16x8*)(bw + 32), acc[t]);
      acc[t] = MFMA16(as0, *(const bf16x8*)bm,        acc[t]);
      acc[t] = MFMA16(as1, *(const bf16x8*)(bm + 32), acc[t]);
    }
    #pragma unroll
    for (int r=0;r<4;r++) {
      int node = m0 + quad*4 + r;
      float dg = dgv[r];
      #pragma unroll
      for (int t=0;t<4;t++) {
        float gi = acc[t][r]     + dg*wbv[0][t] + bsv[0][t];
        float gf = acc[4+t][r]   + dg*wbv[1][t] + bsv[1][t];
        float gg = acc[8+t][r]   + dg*wbv[2][t] + bsv[2][t];
        float go = acc[12+t][r]  + dg*wbv[3][t] + bsv[3][t];
        size_t ci = (size_t)node*64 + t*16 + row;
        float cn = sigf(gf)*cold[t][r] + sigf(gi)*tanhf_fast(gg);
        float hn = sigf(go)*tanhf_fast(cn);
        if (write_c) c[ci] = cn;
        if (!terminal) h_out[ci] = hn;
        hn_[t][r] = hn;
      }
    }
  }

  if (!(fuse_uv | terminal)) return;

  if (active) {
    #pragma unroll
    for (int t=0;t<4;t++)
      #pragma unroll
      for (int r=0;r<4;r++)
        hlds[wib][(quad*4 + r)*68 + t*16 + row] = hn_[t][r];
  }
  __syncthreads();

  if (fuse_uv && active) {
    const float* hr = &hlds[wib][row*68 + quad*8];
    bf16x8 a0 = cvt8(hr);
    bf16x8 a1 = cvt8(hr + 32);
    f32x4 z = {0.f,0.f,0.f,0.f};
    f32x4 au[8];
    #pragma unroll
    for (int t=0;t<8;t++) au[t] = z;
    #pragma unroll
    for (int t=0;t<8;t++) {
      const __bf16* b = Wuvn + (t*16 + row)*64 + quad*8;
      au[t] = MFMA16(a0, *(const bf16x8*)b,        au[t]);
      au[t] = MFMA16(a1, *(const bf16x8*)(b + 32), au[t]);
    }
    #pragma unroll
    for (int t=0;t<8;t++) {
      __bf16* dst = (t < 4) ? U : V;
      int fcol = (t & 3)*16 + row;
      #pragma unroll
      for (int r=0;r<4;r++)
        dst[(size_t)(m0 + quad*4 + r)*64 + fcol] = (__bf16)au[t][r];
    }
  }

  if (terminal) {
    float local[4] = {0.f,0.f,0.f,0.f};
    if (active) {
      const float* hr = &hlds[wib][row*68 + quad*8];
      bf16x8 a0 = cvt8(hr);
      bf16x8 a1 = cvt8(hr + 32);
      f32x4 z = {0.f,0.f,0.f,0.f};
      f32x4 ar[8];
      #pragma unroll
      for (int t=0;t<8;t++) {
        const __bf16* b = R + (t*16 + row)*64 + quad*8;
        ar[t] = MFMA16(a0, *(const bf16x8*)b, z);
        ar[t] = MFMA16(a1, *(const bf16x8*)(b + 32), ar[t]);
      }
      #pragma unroll
      for (int t=0;t<4;t++) {
        int d = t*16 + row;
        if (d < G) {
          float gb = gm_b[d], fb = fm_b[d];
          #pragma unroll
          for (int r=0;r<4;r++) {
            float gv = ar[t][r]   + gb;
            float hv = ar[4+t][r] + fb;
            local[t] += sigf(gv) * hv;
          }
        }
      }
    }
    #pragma unroll
    for (int t=0;t<4;t++) {
      float v = local[t];
      v += __shfl_xor(v, 16);
      v += __shfl_xor(v, 32);
      local[t] = v;
    }
    if (quad == 0)
      #pragma unroll
      for (int t=0;t<4;t++) red[wib][t][row] = local[t];
    __syncthreads();
    if (tid < 64) {
      int d = tid;
      if (d < G) {
        float v = red[0][d>>4][d&15] + red[1][d>>4][d&15] + red[2][d>>4][d&15] + red[3][d>>4][d&15];
        unsafeAtomicAdd(out + d, v);
      }
    }
  }
}

extern "C" void kernel_launch(void* const* d_in, const int* in_sizes, int n_in,
                              void* d_out, int out_size, void* d_ws, size_t ws_size,
                              hipStream_t stream) {
  const float* x         = (const float*)d_in[0];
  const float* edge_attr = (const float*)d_in[1];
  const int*   edge_index= (const int*)  d_in[2];
  const float* fe_w1     = (const float*)d_in[3];
  const float* fe_b1     = (const float*)d_in[4];
  const float* fe_w2     = (const float*)d_in[5];
  const float* fe_b2     = (const float*)d_in[6];
  const float* lstm_wih  = (const float*)d_in[7];
  const float* lstm_whh  = (const float*)d_in[8];
  const float* lstm_bih  = (const float*)d_in[9];
  const float* lstm_bhh  = (const float*)d_in[10];
  const float* gm_w      = (const float*)d_in[11];
  const float* gm_b      = (const float*)d_in[12];
  const float* fm_w      = (const float*)d_in[13];
  const float* fm_b      = (const float*)d_in[14];
  float* out = (float*)d_out;

  const int N  = in_sizes[0] / 64;
  const int E  = in_sizes[1] / 32;
  const int P_ = in_sizes[3] / (64*160);
  const int G  = in_sizes[11] / 64;
  const int nGroups = N / 16;
  const int NW = (N + NBUCK - 1) / NBUCK;   // nodes per bucket (<=512 required)

  // ---- workspace layout (float units) ----
  float* f = (float*)d_ws;
  size_t o = 0;
  float* hA  = f + o;  o += (size_t)N*64;
  float* hB  = f + o;  o += (size_t)N*64;   // for P_==2: dead as h-buffer -> reused as sacc1
  float* cB  = f + o;  o += (size_t)N*64;
  float* sB  = f + o;  o += (size_t)N*64;
  float* wb  = f + o;  o += (size_t)P_*256;
  __bf16* U  = (__bf16*)(f + o);  o += (size_t)N*32;
  __bf16* V  = (__bf16*)(f + o);  o += (size_t)N*32;
  int* degi   = (int*)(f + o);    o += (size_t)N;
  int* bCnt   = (int*)(f + o);    o += NBUCK;
  o = (o + 15) & ~(size_t)15;                        // 64B align
  int2* DS    = (int2*)(f + o);   o += (size_t)E*2;  // packed (dst,src), sorted
  o = (o + 15) & ~(size_t)15;                        // 64B align: EA row == 1 line
  __bf16* EA  = (__bf16*)(f + o); o += ((size_t)E + 64)*16;  // sorted edge_attr, bf16, padded
  unsigned int* entryBuf = (unsigned int*)(f + o); o += (size_t)NBUCK*CAPG;
  __bf16* Wuv = (__bf16*)(f + o);
  __bf16* Wc  = Wuv + (size_t)P_*128*64;
  __bf16* Wih = Wc  + (size_t)P_*64*32;
  __bf16* Mw  = Wih + (size_t)P_*256*64;
  __bf16* Rw  = Mw  + (size_t)P_*256*64;

  // sacc ping-pong: hB is provably unused as an h-buffer when P_==2
  // (terminal step never writes h_out), so reuse it -> zero extra footprint.
  const int pingpong = (P_ == 2);

  hipMemsetAsync(out, 0, (size_t)out_size*sizeof(float), stream);
  hipMemsetAsync(bCnt, 0, NBUCK*sizeof(int), stream);

  // p1 (+ prep_all + zero-sacc0 + step0-prep_uv tails, all in p1's DRAM slack)
  int nb1 = (E + P1_ED - 1) / P1_ED;
  {
    int tot = P_*256*64 + P_*128*64 + P_*64*32 + P_*256*64 + 128*64;
    int prepB = (tot + 255)/256;
    int zB = 192;
    int uvB = (nGroups + 3) / 4;
    k_p1_bucket<<<nb1 + prepB + zB + uvB, 256, 0, stream>>>(
        edge_index, entryBuf, bCnt, E, NW, nb1, prepB, zB,
        lstm_whh, fe_w2, fe_b2, fe_w1, lstm_wih, gm_w, fm_w,
        Mw, wb, Wuv, Wc, Wih, Rw, P_, G,
        x, U, V, sB, N, nGroups);
  }

  // p2: sort + emit, gstart computed inline
  k_p2_sort<<<NBUCK*SPLIT, 512, 0, stream>>>(entryBuf, bCnt, edge_index,
                                             edge_attr, DS, EA, degi, E, N, NW);

  int nodeBlocks = (nGroups + 3) / 4;
  int chunkBlocks = ((E + 63)/64 + 3) / 4;

  for (int i = 0; i < P_; i++) {
    const float* h_in = (i == 0) ? x : ((i & 1) ? hA : hB);
    float*       h_out = (i & 1) ? hB : hA;
    int terminal = (i == P_ - 1);
    int fuse_uv  = !terminal;

    float* sacc_i = (pingpong && (i & 1)) ? hB : sB;
    float* sZero  = (pingpong && !terminal) ? (((i+1) & 1) ? hB : sB) : (float*)nullptr;

    if (!pingpong && i > 0)
      hipMemsetAsync(sB, 0, (size_t)N*64*sizeof(float), stream);

    int zB2 = sZero ? 320 : 0;
    k_aggr_e<<<chunkBlocks + zB2, 256, 0, stream>>>(DS, EA, Wc + (size_t)i*64*32,
                                                    fe_b1 + i*64, U, V, sacc_i, E,
                                                    sZero, N, chunkBlocks);
    k_lstm<<<nodeBlocks, 256, 0, stream>>>(h_in, sacc_i, degi,
                                           Wih + (size_t)i*256*64, Mw + (size_t)i*256*64,
                                           wb + i*256, lstm_bih + i*256, lstm_bhh + i*256,
                                           h_out, cB,
                                           Wuv + (size_t)(i+1 < P_ ? i+1 : 0)*128*64, U, V,
                                           Rw, gm_b, fm_b, out,
                                           nGroups, G,
                                           /*has_c=*/(i > 0), /*write_c=*/(i < P_-1),
                                           fuse_uv, terminal);
  }
}

// Round 9
// 755.824 us; speedup vs baseline: 1.0066x; 1.0009x over previous
//
#include <hip/hip_runtime.h>
#include <hip/hip_bf16.h>
#include <math.h>

typedef __bf16  bf16x8 __attribute__((ext_vector_type(8)));
typedef float   f32x4  __attribute__((ext_vector_type(4)));

#define MFMA16(a,b,c) __builtin_amdgcn_mfma_f32_16x16x32_bf16((a),(b),(c),0,0,0)

#define NBUCK 256
#define CAPG  8192      // max entries per bucket segment (mean ~6250, +24 sigma)
#define P1_ED 4096      // edges per p1 block
#define SPLIT 4         // emit-quarters per bucket

__device__ __forceinline__ bf16x8 cvt8(const float* p) {
  const f32x4* q = (const f32x4*)p;
  f32x4 u = q[0], v = q[1];
  bf16x8 r;
  r[0]=(__bf16)u[0]; r[1]=(__bf16)u[1]; r[2]=(__bf16)u[2]; r[3]=(__bf16)u[3];
  r[4]=(__bf16)v[0]; r[5]=(__bf16)v[1]; r[6]=(__bf16)v[2]; r[7]=(__bf16)v[3];
  return r;
}

__device__ __forceinline__ float sigf(float x){ return 1.0f/(1.0f + __expf(-x)); }
__device__ __forceinline__ float tanhf_fast(float x){
  float ax = fabsf(x);
  float t = __expf(-2.f*ax);
  float r = (1.f - t)/(1.f + t);
  return copysignf(r, x);
}

// ---------------- pass 1 + streaming tails -----------------------------------
// Blocks [0,nMain):              block-aggregated bucket scatter of edges.
// Blocks [nMain, +prepB):        weight prep (prep_all).
// Blocks [nMain+prepB, +convB):  edge_attr fp32 -> bf16 conversion (EAb,
//                                unsorted, fully coalesced). p1 main is
//                                LDS-sort-heavy / DRAM-light -> slack.
__global__ __launch_bounds__(256) void k_p1_bucket(const int* __restrict__ ei,
                                                   unsigned int* __restrict__ entryBuf,
                                                   int* __restrict__ bCnt,
                                                   int E, int NW, int nMain,
                                                   int prepB, int convB,
                                                   const float* __restrict__ whh,
                                                   const float* __restrict__ w2,
                                                   const float* __restrict__ b2,
                                                   const float* __restrict__ fe_w1,
                                                   const float* __restrict__ lstm_wih,
                                                   const float* __restrict__ gm_w,
                                                   const float* __restrict__ fm_w,
                                                   __bf16* __restrict__ Mout,
                                                   float* __restrict__ wb,
                                                   __bf16* __restrict__ Wuv,
                                                   __bf16* __restrict__ Wc,
                                                   __bf16* __restrict__ Wih,
                                                   __bf16* __restrict__ R,
                                                   int P_, int G,
                                                   const float* __restrict__ ea,
                                                   __bf16* __restrict__ EAb) {
  __shared__ unsigned int hin[NBUCK], hof[NBUCK], hcur[NBUCK], gbase[NBUCK];
  __shared__ unsigned int vals[P1_ED];
  __shared__ unsigned int gpos[P1_ED];
  __shared__ unsigned int totS;
  int tid = threadIdx.x;

  if ((int)blockIdx.x >= nMain) {
    int tb = (int)blockIdx.x - nMain;
    if (tb < prepB) {
      // ---- prep_all tail ----
      int idx = tb*256 + tid;
      int n0 = P_*256*64;
      if (idx < n0) {
        int c = idx & 63; int r = (idx >> 6) & 255; int i = idx >> 14;
        const float* wh  = whh + ((size_t)i*256 + r)*64;
        const float* w2i = w2  + (size_t)i*64*64;
        float acc = 0.f;
        #pragma unroll 8
        for (int j=0;j<64;j++) acc += wh[j] * w2i[j*64 + c];
        Mout[idx] = (__bf16)acc;
        if (c == 0) {
          const float* b2i = b2 + i*64;
          float a2 = 0.f;
          for (int j=0;j<64;j++) a2 += wh[j]*b2i[j];
          wb[i*256 + r] = a2;
        }
        return;
      }
      idx -= n0;
      int nA = P_*128*64, nB = P_*64*32, nC = P_*256*64, nD = 128*64;
      if (idx < nA) {
        int k = idx & 63, j = (idx >> 6) & 127, i = idx >> 13;
        Wuv[idx] = (__bf16)fe_w1[(size_t)i*10240 + (j&63)*160 + (j>>6)*64 + k];
        return;
      }
      idx -= nA;
      if (idx < nB) {
        int k = idx & 31, j = (idx >> 5) & 63, i = idx >> 11;
        Wc[idx] = (__bf16)fe_w1[(size_t)i*10240 + j*160 + 128 + k];
        return;
      }
      idx -= nB;
      if (idx < nC) { Wih[idx] = (__bf16)lstm_wih[idx]; return; }
      idx -= nC;
      if (idx < nD) {
        int k = idx & 63, j = idx >> 6;
        float v = 0.f;
        if (j < G) v = gm_w[j*64 + k];
        else if (j >= 64 && j < 64 + G) v = fm_w[(j-64)*64 + k];
        R[idx] = (__bf16)v;
      }
      return;
    }
    tb -= prepB;
    // ---- edge_attr -> bf16 streaming conversion (grid-stride, coalesced) ----
    {
      size_t nchunks = (size_t)E*4;        // 8-float chunks
      size_t nt = (size_t)convB*256;
      for (size_t c = (size_t)tb*256 + tid; c < nchunks; c += nt)
        *(bf16x8*)(EAb + c*8) = cvt8(ea + c*8);
    }
    return;
  }

  // ---- p1 main ----
  hin[tid] = 0;
  __syncthreads();

  int e0 = blockIdx.x * P1_ED;
  unsigned int myb[16], myv[16];
  #pragma unroll
  for (int k=0;k<16;k++) {
    int e = e0 + k*256 + tid;
    if (e < E) {
      int d = ei[E + e];
      int b = d / NW;
      int dl = d - b*NW;
      myb[k] = (unsigned int)b;
      myv[k] = ((unsigned int)dl << 21) | (unsigned int)e;
      atomicAdd(&hin[b], 1u);
    } else myb[k] = 0xFFFFFFFFu;
  }
  __syncthreads();

  unsigned int cntb = hin[tid];
  hof[tid] = cntb;
  __syncthreads();
  #pragma unroll
  for (int off=1; off<NBUCK; off<<=1) {
    unsigned int a = (tid >= off) ? hof[tid-off] : 0u;
    __syncthreads();
    hof[tid] += a;
    __syncthreads();
  }
  unsigned int excl = hof[tid] - cntb;
  if (cntb > 0) gbase[tid] = (unsigned int)atomicAdd(&bCnt[tid], (int)cntb);
  if (tid == NBUCK-1) totS = excl + cntb;
  __syncthreads();
  hof[tid] = excl;
  hcur[tid] = excl;
  __syncthreads();

  #pragma unroll
  for (int k=0;k<16;k++) {
    if (myb[k] != 0xFFFFFFFFu) {
      unsigned int b = myb[k];
      unsigned int pos = atomicAdd(&hcur[b], 1u);
      vals[pos] = myv[k];
      unsigned int go = gbase[b] + (pos - hof[b]);
      gpos[pos] = (go < CAPG) ? (b*CAPG + go) : 0xFFFFFFFFu;
    }
  }
  __syncthreads();
  unsigned int tot = totS;
  for (unsigned int i = tid; i < tot; i += 256) {
    unsigned int g = gpos[i];
    if (g != 0xFFFFFFFFu) entryBuf[g] = vals[i];
  }
}

// ---------------- pass 2: counting sort + LIGHT emit + tails -----------------
// Emit writes only DS (dst,src), Eidx (orig edge id) and degi -- NO edge
// payload gather (that moved to aggr via Eidx). p2 is now DRAM-light, so the
// zero-sacc0 and step-0 prep_uv tails ride here.
// Blocks [0,nMain): sort+emit. [nMain,+zB): zero sacc0 (+Eidx pad).
// [nMain+zB,..): step-0 prep_uv (8 waves/block).
__global__ __launch_bounds__(512) void k_p2_sort(const unsigned int* __restrict__ entryBuf,
                                                 const int* __restrict__ bCnt,
                                                 const int* __restrict__ ei,
                                                 int2* __restrict__ DS,
                                                 int* __restrict__ Eidx,
                                                 int* __restrict__ degi,
                                                 int E, int N, int NW,
                                                 int nMain, int zB,
                                                 const float* __restrict__ x,
                                                 const __bf16* __restrict__ Wuv0,
                                                 __bf16* __restrict__ U,
                                                 __bf16* __restrict__ V,
                                                 float* __restrict__ sacc0,
                                                 int nGroups) {
  __shared__ unsigned int hist[512], hof[512], hcur[512];
  __shared__ unsigned int evals[CAPG];
  __shared__ unsigned int gp0S;
  int tid = threadIdx.x;

  if ((int)blockIdx.x >= nMain) {
    int tb = (int)blockIdx.x - nMain;
    if (tb < zB) {
      if (tb == 0 && tid < 64) Eidx[E + tid] = 0;   // pad for aggr fragment loads
      f32x4 z4 = {0.f,0.f,0.f,0.f};
      f32x4* p = (f32x4*)sacc0;
      size_t tot4 = (size_t)N*16;
      size_t nt = (size_t)zB*512;
      for (size_t i = (size_t)tb*512 + tid; i < tot4; i += nt) p[i] = z4;
      return;
    }
    tb -= zB;
    int wave = tb*8 + (tid >> 6);
    if (wave >= nGroups) return;
    int lane = tid & 63, row = lane & 15, quad = lane >> 4;
    int m0 = wave * 16;
    const float* arow = x + (size_t)(m0 + row)*64 + quad*8;
    bf16x8 a0 = cvt8(arow);
    bf16x8 a1 = cvt8(arow + 32);
    f32x4 z = {0.f,0.f,0.f,0.f};
    f32x4 acc[8];
    #pragma unroll
    for (int t=0;t<8;t++) acc[t] = z;
    #pragma unroll
    for (int t=0;t<8;t++) {
      const __bf16* b = Wuv0 + (t*16 + row)*64 + quad*8;
      acc[t] = MFMA16(a0, *(const bf16x8*)b,        acc[t]);
      acc[t] = MFMA16(a1, *(const bf16x8*)(b + 32), acc[t]);
    }
    #pragma unroll
    for (int t=0;t<8;t++) {
      __bf16* dst = (t < 4) ? U : V;
      int fcol = (t & 3)*16 + row;
      #pragma unroll
      for (int r=0;r<4;r++)
        dst[(size_t)(m0 + quad*4 + r)*64 + fcol] = (__bf16)acc[t][r];
    }
    return;
  }

  int b = blockIdx.x >> 2;         // SPLIT == 4
  int q = blockIdx.x & 3;
  unsigned int cnt = (unsigned int)min(bCnt[b], CAPG);
  const unsigned int* seg = entryBuf + (size_t)b*CAPG;

  // inline gstart[b]: exclusive prefix over clamped bucket counts
  {
    unsigned int v = (tid < NBUCK) ? (unsigned int)min(bCnt[tid], CAPG) : 0u;
    hof[tid] = v;
    __syncthreads();
    #pragma unroll
    for (int off=1; off<512; off<<=1) {
      unsigned int a = (tid >= off) ? hof[tid-off] : 0u;
      __syncthreads();
      hof[tid] += a;
      __syncthreads();
    }
    if (tid == 0) gp0S = (b > 0) ? hof[b-1] : 0u;
    __syncthreads();
  }

  hist[tid] = 0;
  __syncthreads();
  for (unsigned int i = tid; i < cnt; i += 512) atomicAdd(&hist[seg[i] >> 21], 1u);
  __syncthreads();

  unsigned int h = hist[tid];
  hof[tid] = h;
  __syncthreads();
  #pragma unroll
  for (int off=1; off<512; off<<=1) {
    unsigned int a = (tid >= off) ? hof[tid-off] : 0u;
    __syncthreads();
    hof[tid] += a;
    __syncthreads();
  }
  unsigned int excl = hof[tid] - h;
  int d0 = b*NW + tid;
  if (tid < NW && d0 < N) degi[d0] = (int)h;
  hcur[tid] = excl;
  __syncthreads();

  for (unsigned int i = tid; i < cnt; i += 512) {
    unsigned int v = seg[i];
    unsigned int pos = atomicAdd(&hcur[v >> 21], 1u);
    evals[pos] = v;
  }
  __syncthreads();

  unsigned int gp0 = gp0S;
  unsigned int lo = (cnt * (unsigned int)q) >> 2;
  unsigned int hi = (cnt * (unsigned int)(q+1)) >> 2;
  for (unsigned int i = lo + tid; i < hi; i += 512) {
    unsigned int v = evals[i];
    unsigned int e = v & 0x1FFFFFu;
    int dl = (int)(v >> 21);
    int d  = b*NW + dl;
    int s  = ei[e];
    size_t p = (size_t)gp0 + i;
    int2 ds; ds.x = d; ds.y = s;
    DS[p] = ds;
    Eidx[p] = (int)e;
  }
}

// ---------------- edge-centric aggregation + zero tail -----------------------
// EA fragments gathered from unsorted EAb via Eidx (random 64B rows; half the
// line count of the old fp32 gather, and plausibly L3-warm). aggr's high
// occupancy pipelines the latency.
__global__ __launch_bounds__(256) void k_aggr_e(const int2* __restrict__ DS,
                                                const int* __restrict__ Eidx,
                                                const __bf16* __restrict__ EAb,
                                                const __bf16* __restrict__ Wc,
                                                const float* __restrict__ b1,
                                                const __bf16* __restrict__ U,
                                                const __bf16* __restrict__ V,
                                                float* __restrict__ sacc, int E,
                                                float* __restrict__ sZero, int Nn,
                                                int nMain) {
  __shared__ float ldsb[4][16*68];   // stride 68: conflict-free (2 lanes/bank)
  int tid = threadIdx.x;

  if ((int)blockIdx.x >= nMain) {
    if (sZero) {
      f32x4 z4 = {0.f,0.f,0.f,0.f};
      f32x4* p = (f32x4*)sZero;
      size_t tot4 = (size_t)Nn*16;
      size_t nt = (size_t)(gridDim.x - nMain)*256;
      for (size_t i = ((size_t)blockIdx.x - nMain)*256 + tid; i < tot4; i += nt) p[i] = z4;
    }
    return;
  }

  int wib = tid >> 6;
  int lane = tid & 63, row = lane & 15, quad = lane >> 4;

  int e0 = ((int)blockIdx.x*4 + wib) * 64;
  if (e0 >= E) return;

  int eidx = min(e0 + lane, E - 1);
  int2 dsv = DS[eidx];
  int dv = dsv.x;
  int sv = dsv.y;

  int prevd = __shfl_up(dv, 1);
  unsigned long long bmask = __ballot((lane == 0) || (dv != prevd));

  // EA fragments via Eidx indirection (Eidx padded past E -> row 0, masked out)
  bf16x8 a[4];
  #pragma unroll
  for (int st=0;st<4;st++) {
    int eo = Eidx[e0 + st*16 + row];
    a[st] = *(const bf16x8*)(EAb + (size_t)eo*32 + quad*8);
  }

  bf16x8 bfr[4]; float bias[4];
  #pragma unroll
  for (int t=0;t<4;t++) {
    bfr[t] = *(const bf16x8*)(Wc + (t*16 + row)*32 + quad*8);
    bias[t] = b1[t*16 + row];
  }

  __bf16 uu[2][16], vv[2][16];
  #pragma unroll
  for (int r=0;r<16;r++) {
    int s = __builtin_amdgcn_readlane(sv, r);
    int d = __builtin_amdgcn_readlane(dv, r);
    vv[0][r] = V[(size_t)s*64 + lane];
    uu[0][r] = U[(size_t)d*64 + lane];
  }

  float acc = 0.f;
  int dcur = __builtin_amdgcn_readlane(dv, 0);
  float* L = &ldsb[wib][0];
  f32x4 z = {0.f,0.f,0.f,0.f};

  #pragma unroll
  for (int st=0; st<4; st++) {
    const int cur = st & 1, nxt = cur ^ 1;
    #pragma unroll
    for (int t=0;t<4;t++) {
      f32x4 c4 = MFMA16(a[st], bfr[t], z);
      #pragma unroll
      for (int r=0;r<4;r++)
        L[(quad*4 + r)*68 + t*16 + row] = c4[r] + bias[t];
    }
    if (st < 3) {
      #pragma unroll
      for (int r=0;r<16;r++) {
        int s = __builtin_amdgcn_readlane(sv, (st+1)*16 + r);
        int d = __builtin_amdgcn_readlane(dv, (st+1)*16 + r);
        vv[nxt][r] = V[(size_t)s*64 + lane];
        uu[nxt][r] = U[(size_t)d*64 + lane];
      }
    }
    #pragma unroll
    for (int r=0;r<16;r++) {
      const int idx = st*16 + r;
      if (idx > 0 && (bmask & (1ull << idx))) {
        unsafeAtomicAdd(&sacc[(size_t)dcur*64 + lane], acc);
        acc = 0.f;
        dcur = __builtin_amdgcn_readlane(dv, idx);
      }
      if (e0 + idx < E) {
        float t2 = (float)uu[cur][r] + (float)vv[cur][r] + L[r*68 + lane];
        acc += t2 > 0.f ? t2 : 0.f;
      }
    }
  }
  unsafeAtomicAdd(&sacc[(size_t)dcur*64 + lane], acc);
}

// ---------------- K4: gates + LSTM update, with fused epilogues ----------------
__global__ __launch_bounds__(256) void k_lstm(const float* __restrict__ h_in,
                                              const float* __restrict__ sacc,
                                              const int* __restrict__ degi,
                                              const __bf16* __restrict__ Wih,
                                              const __bf16* __restrict__ Mw,
                                              const float* __restrict__ wb,
                                              const float* __restrict__ bih,
                                              const float* __restrict__ bhh,
                                              float* __restrict__ h_out,
                                              float* __restrict__ c,
                                              const __bf16* __restrict__ Wuvn,
                                              __bf16* __restrict__ U,
                                              __bf16* __restrict__ V,
                                              const __bf16* __restrict__ R,
                                              const float* __restrict__ gm_b,
                                              const float* __restrict__ fm_b,
                                              float* __restrict__ out,
                                              int nGroups, int G,
                                              int has_c, int write_c,
                                              int fuse_uv, int terminal) {
  __shared__ float hlds[4][16*68];
  __shared__ float red[4][4][16];
  int tid = threadIdx.x;
  int wave = (blockIdx.x*blockDim.x + tid) >> 6;
  int wib  = tid >> 6;
  int lane = tid & 63, row = lane & 15, quad = lane >> 4;
  bool active = (wave < nGroups);
  int m0 = wave * 16;

  float hn_[4][4];
  if (active) {
    float wbv[4][4], bsv[4][4];
    #pragma unroll
    for (int g=0; g<4; g++)
      #pragma unroll
      for (int t=0; t<4; t++) {
        int dcol = g*64 + t*16 + row;
        wbv[g][t] = wb[dcol];
        bsv[g][t] = bih[dcol] + bhh[dcol];
      }
    float dgv[4];
    #pragma unroll
    for (int r=0;r<4;r++) {
      int node = m0 + quad*4 + r;
      dgv[r] = (float)degi[node];
    }
    float cold[4][4];
    if (has_c) {
      #pragma unroll
      for (int t=0;t<4;t++)
        #pragma unroll
        for (int r=0;r<4;r++)
          cold[t][r] = c[(size_t)(m0 + quad*4 + r)*64 + t*16 + row];
    } else {
      #pragma unroll
      for (int t=0;t<4;t++)
        #pragma unroll
        for (int r=0;r<4;r++) cold[t][r] = 0.f;
    }

    const float* hrow = h_in + (size_t)(m0 + row)*64 + quad*8;
    const float* srow = sacc + (size_t)(m0 + row)*64 + quad*8;
    bf16x8 ah0 = cvt8(hrow), ah1 = cvt8(hrow + 32);
    bf16x8 as0 = cvt8(srow), as1 = cvt8(srow + 32);
    f32x4 z = {0.f,0.f,0.f,0.f};
    f32x4 acc[16];
    #pragma unroll
    for (int t=0;t<16;t++) acc[t] = z;
    #pragma unroll
    for (int t=0;t<16;t++) {
      const __bf16* bw = Wih + (t*16 + row)*64 + quad*8;
      const __bf16* bm = Mw  + (t*16 + row)*64 + quad*8;
      acc[t] = MFMA16(ah0, *(const bf16x8*)bw,        acc[t]);
      acc[t] = MFMA16(ah1, *(const bf16x8*)(bw + 32), acc[t]);
      acc[t] = MFMA16(as0, *(const bf16x8*)bm,        acc[t]);
      acc[t] = MFMA16(as1, *(const bf16x8*)(bm + 32), acc[t]);
    }
    #pragma unroll
    for (int r=0;r<4;r++) {
      int node = m0 + quad*4 + r;
      float dg = dgv[r];
      #pragma unroll
      for (int t=0;t<4;t++) {
        float gi = acc[t][r]     + dg*wbv[0][t] + bsv[0][t];
        float gf = acc[4+t][r]   + dg*wbv[1][t] + bsv[1][t];
        float gg = acc[8+t][r]   + dg*wbv[2][t] + bsv[2][t];
        float go = acc[12+t][r]  + dg*wbv[3][t] + bsv[3][t];
        size_t ci = (size_t)node*64 + t*16 + row;
        float cn = sigf(gf)*cold[t][r] + sigf(gi)*tanhf_fast(gg);
        float hn = sigf(go)*tanhf_fast(cn);
        if (write_c) c[ci] = cn;
        if (!terminal) h_out[ci] = hn;
        hn_[t][r] = hn;
      }
    }
  }

  if (!(fuse_uv | terminal)) return;

  if (active) {
    #pragma unroll
    for (int t=0;t<4;t++)
      #pragma unroll
      for (int r=0;r<4;r++)
        hlds[wib][(quad*4 + r)*68 + t*16 + row] = hn_[t][r];
  }
  __syncthreads();

  if (fuse_uv && active) {
    const float* hr = &hlds[wib][row*68 + quad*8];
    bf16x8 a0 = cvt8(hr);
    bf16x8 a1 = cvt8(hr + 32);
    f32x4 z = {0.f,0.f,0.f,0.f};
    f32x4 au[8];
    #pragma unroll
    for (int t=0;t<8;t++) au[t] = z;
    #pragma unroll
    for (int t=0;t<8;t++) {
      const __bf16* b = Wuvn + (t*16 + row)*64 + quad*8;
      au[t] = MFMA16(a0, *(const bf16x8*)b,        au[t]);
      au[t] = MFMA16(a1, *(const bf16x8*)(b + 32), au[t]);
    }
    #pragma unroll
    for (int t=0;t<8;t++) {
      __bf16* dst = (t < 4) ? U : V;
      int fcol = (t & 3)*16 + row;
      #pragma unroll
      for (int r=0;r<4;r++)
        dst[(size_t)(m0 + quad*4 + r)*64 + fcol] = (__bf16)au[t][r];
    }
  }

  if (terminal) {
    float local[4] = {0.f,0.f,0.f,0.f};
    if (active) {
      const float* hr = &hlds[wib][row*68 + quad*8];
      bf16x8 a0 = cvt8(hr);
      bf16x8 a1 = cvt8(hr + 32);
      f32x4 z = {0.f,0.f,0.f,0.f};
      f32x4 ar[8];
      #pragma unroll
      for (int t=0;t<8;t++) {
        const __bf16* b = R + (t*16 + row)*64 + quad*8;
        ar[t] = MFMA16(a0, *(const bf16x8*)b, z);
        ar[t] = MFMA16(a1, *(const bf16x8*)(b + 32), ar[t]);
      }
      #pragma unroll
      for (int t=0;t<4;t++) {
        int d = t*16 + row;
        if (d < G) {
          float gb = gm_b[d], fb = fm_b[d];
          #pragma unroll
          for (int r=0;r<4;r++) {
            float gv = ar[t][r]   + gb;
            float hv = ar[4+t][r] + fb;
            local[t] += sigf(gv) * hv;
          }
        }
      }
    }
    #pragma unroll
    for (int t=0;t<4;t++) {
      float v = local[t];
      v += __shfl_xor(v, 16);
      v += __shfl_xor(v, 32);
      local[t] = v;
    }
    if (quad == 0)
      #pragma unroll
      for (int t=0;t<4;t++) red[wib][t][row] = local[t];
    __syncthreads();
    if (tid < 64) {
      int d = tid;
      if (d < G) {
        float v = red[0][d>>4][d&15] + red[1][d>>4][d&15] + red[2][d>>4][d&15] + red[3][d>>4][d&15];
        unsafeAtomicAdd(out + d, v);
      }
    }
  }
}

extern "C" void kernel_launch(void* const* d_in, const int* in_sizes, int n_in,
                              void* d_out, int out_size, void* d_ws, size_t ws_size,
                              hipStream_t stream) {
  const float* x         = (const float*)d_in[0];
  const float* edge_attr = (const float*)d_in[1];
  const int*   edge_index= (const int*)  d_in[2];
  const float* fe_w1     = (const float*)d_in[3];
  const float* fe_b1     = (const float*)d_in[4];
  const float* fe_w2     = (const float*)d_in[5];
  const float* fe_b2     = (const float*)d_in[6];
  const float* lstm_wih  = (const float*)d_in[7];
  const float* lstm_whh  = (const float*)d_in[8];
  const float* lstm_bih  = (const float*)d_in[9];
  const float* lstm_bhh  = (const float*)d_in[10];
  const float* gm_w      = (const float*)d_in[11];
  const float* gm_b      = (const float*)d_in[12];
  const float* fm_w      = (const float*)d_in[13];
  const float* fm_b      = (const float*)d_in[14];
  float* out = (float*)d_out;

  const int N  = in_sizes[0] / 64;
  const int E  = in_sizes[1] / 32;
  const int P_ = in_sizes[3] / (64*160);
  const int G  = in_sizes[11] / 64;
  const int nGroups = N / 16;
  const int NW = (N + NBUCK - 1) / NBUCK;   // nodes per bucket (<=512 required)

  // ---- workspace layout (float units) ----
  float* f = (float*)d_ws;
  size_t o = 0;
  float* hA  = f + o;  o += (size_t)N*64;
  float* hB  = f + o;  o += (size_t)N*64;   // for P_==2: dead as h-buffer -> reused as sacc1
  float* cB  = f + o;  o += (size_t)N*64;
  float* sB  = f + o;  o += (size_t)N*64;
  float* wb  = f + o;  o += (size_t)P_*256;
  __bf16* U  = (__bf16*)(f + o);  o += (size_t)N*32;
  __bf16* V  = (__bf16*)(f + o);  o += (size_t)N*32;
  int* degi   = (int*)(f + o);    o += (size_t)N;
  int* bCnt   = (int*)(f + o);    o += NBUCK;
  o = (o + 15) & ~(size_t)15;                        // 64B align
  int2* DS    = (int2*)(f + o);   o += (size_t)E*2;  // packed (dst,src), sorted
  int* Eidx   = (int*)(f + o);    o += (size_t)E + 64;  // orig edge id, sorted (+pad)
  o = (o + 15) & ~(size_t)15;                        // 64B align: EAb row == 1 line
  __bf16* EAb = (__bf16*)(f + o); o += (size_t)E*16;    // bf16 edge_attr, UNSORTED
  unsigned int* entryBuf = (unsigned int*)(f + o); o += (size_t)NBUCK*CAPG;
  __bf16* Wuv = (__bf16*)(f + o);
  __bf16* Wc  = Wuv + (size_t)P_*128*64;
  __bf16* Wih = Wc  + (size_t)P_*64*32;
  __bf16* Mw  = Wih + (size_t)P_*256*64;
  __bf16* Rw  = Mw  + (size_t)P_*256*64;

  const int pingpong = (P_ == 2);

  hipMemsetAsync(out, 0, (size_t)out_size*sizeof(float), stream);
  hipMemsetAsync(bCnt, 0, NBUCK*sizeof(int), stream);

  // p1 (+ prep_all + edge_attr->bf16 conversion tails)
  int nb1 = (E + P1_ED - 1) / P1_ED;
  {
    int tot = P_*256*64 + P_*128*64 + P_*64*32 + P_*256*64 + 128*64;
    int prepB = (tot + 255)/256;
    int convB = 768;
    k_p1_bucket<<<nb1 + prepB + convB, 256, 0, stream>>>(
        edge_index, entryBuf, bCnt, E, NW, nb1, prepB, convB,
        lstm_whh, fe_w2, fe_b2, fe_w1, lstm_wih, gm_w, fm_w,
        Mw, wb, Wuv, Wc, Wih, Rw, P_, G,
        edge_attr, EAb);
  }

  // p2: sort + light emit (DS, Eidx, degi) + zero-sacc0 + step-0 prep_uv tails
  {
    int nMain = NBUCK*SPLIT;
    int zB = 192;
    int uvB = (nGroups + 7) / 8;
    k_p2_sort<<<nMain + zB + uvB, 512, 0, stream>>>(entryBuf, bCnt, edge_index,
                                                    DS, Eidx, degi, E, N, NW,
                                                    nMain, zB, x, Wuv, U, V, sB, nGroups);
  }

  int nodeBlocks = (nGroups + 3) / 4;
  int chunkBlocks = ((E + 63)/64 + 3) / 4;

  for (int i = 0; i < P_; i++) {
    const float* h_in = (i == 0) ? x : ((i & 1) ? hA : hB);
    float*       h_out = (i & 1) ? hB : hA;
    int terminal = (i == P_ - 1);
    int fuse_uv  = !terminal;

    float* sacc_i = (pingpong && (i & 1)) ? hB : sB;
    float* sZero  = (pingpong && !terminal) ? (((i+1) & 1) ? hB : sB) : (float*)nullptr;

    if (!pingpong && i > 0)
      hipMemsetAsync(sB, 0, (size_t)N*64*sizeof(float), stream);

    int zB2 = sZero ? 320 : 0;
    k_aggr_e<<<chunkBlocks + zB2, 256, 0, stream>>>(DS, Eidx, EAb, Wc + (size_t)i*64*32,
                                                    fe_b1 + i*64, U, V, sacc_i, E,
                                                    sZero, N, chunkBlocks);
    k_lstm<<<nodeBlocks, 256, 0, stream>>>(h_in, sacc_i, degi,
                                           Wih + (size_t)i*256*64, Mw + (size_t)i*256*64,
                                           wb + i*256, lstm_bih + i*256, lstm_bhh + i*256,
                                           h_out, cB,
                                           Wuv + (size_t)(i+1 < P_ ? i+1 : 0)*128*64, U, V,
                                           Rw, gm_b, fm_b, out,
                                           nGroups, G,
                                           /*has_c=*/(i > 0), /*write_c=*/(i < P_-1),
                                           fuse_uv, terminal);
  }
}